// Round 1
// baseline (175.967 us; speedup 1.0000x reference)
//
#include <hip/hip_runtime.h>
#include <hip/hip_bf16.h>

// Stratified max pooling: out[b,c] = max over j with labels[j]==c of values[b,j]
// values: [B, N] fp32, labels: [N] int, out: [B, C] fp32.
// Strategy: monotone float->uint encoding so max == integer max; LDS atomic
// scatter-max per (row-group, column-chunk) block; global atomicMax flush into
// d_out (as u32); final in-place decode kernel.

#define TPB   256
#define ROWS  8      // rows per block
#define CHUNK 4096   // columns per block (TPB threads * 16 cols each)
#define CPAD  257    // LDS stride (supports C <= 256; breaks bank patterns)

#define ENC_NEG_INF 0x007FFFFFu   // enc(-inf)

__device__ __forceinline__ unsigned enc(float f) {
    unsigned u = __float_as_uint(f);
    return (u & 0x80000000u) ? ~u : (u | 0x80000000u);
}
__device__ __forceinline__ float dec(unsigned u) {
    unsigned b = (u & 0x80000000u) ? (u & 0x7FFFFFFFu) : ~u;
    return __uint_as_float(b);
}

__global__ __launch_bounds__(TPB) void strat_init(unsigned* __restrict__ out_enc, int n) {
    int i = blockIdx.x * TPB + threadIdx.x;
    if (i < n) out_enc[i] = ENC_NEG_INF;
}

__global__ __launch_bounds__(TPB) void strat_main(
    const float* __restrict__ values, const int* __restrict__ labels,
    unsigned* __restrict__ out_enc, int B, int N, int C) {
    __shared__ unsigned acc[ROWS * CPAD];

    const int tid    = threadIdx.x;
    const int chunk0 = blockIdx.x * CHUNK;
    const int row0   = blockIdx.y * ROWS;

    for (int i = tid; i < ROWS * CPAD; i += TPB) acc[i] = ENC_NEG_INF;
    __syncthreads();

    const int rmax = min(ROWS, B - row0);
    const bool full_chunk = (chunk0 + CHUNK <= N);

    if (full_chunk) {
        // 16 labels per thread, read once per block, kept in registers.
        int4 L[4];
#pragma unroll
        for (int k = 0; k < 4; ++k)
            L[k] = ((const int4*)(labels + chunk0 + k * 1024))[tid];

        if (rmax == ROWS) {
#pragma unroll
            for (int r = 0; r < ROWS; ++r) {
                const float4* src =
                    (const float4*)(values + (size_t)(row0 + r) * N + chunk0) + tid;
                float4 v[4];
#pragma unroll
                for (int k = 0; k < 4; ++k) v[k] = src[k * 256];
                unsigned* accr = acc + r * CPAD;
#pragma unroll
                for (int k = 0; k < 4; ++k) {
                    atomicMax(&accr[L[k].x], enc(v[k].x));
                    atomicMax(&accr[L[k].y], enc(v[k].y));
                    atomicMax(&accr[L[k].z], enc(v[k].z));
                    atomicMax(&accr[L[k].w], enc(v[k].w));
                }
            }
        } else {
            for (int r = 0; r < rmax; ++r) {
                const float4* src =
                    (const float4*)(values + (size_t)(row0 + r) * N + chunk0) + tid;
                float4 v[4];
#pragma unroll
                for (int k = 0; k < 4; ++k) v[k] = src[k * 256];
                unsigned* accr = acc + r * CPAD;
#pragma unroll
                for (int k = 0; k < 4; ++k) {
                    atomicMax(&accr[L[k].x], enc(v[k].x));
                    atomicMax(&accr[L[k].y], enc(v[k].y));
                    atomicMax(&accr[L[k].z], enc(v[k].z));
                    atomicMax(&accr[L[k].w], enc(v[k].w));
                }
            }
        }
    } else {
        // Tail chunk: per-element guarded loads (runs on 1 of 49 chunks only).
        for (int r = 0; r < rmax; ++r) {
            unsigned* accr = acc + r * CPAD;
            const size_t rowoff = (size_t)(row0 + r) * N;
            for (int k = 0; k < 4; ++k) {
                int j = chunk0 + k * 1024 + tid * 4;
#pragma unroll
                for (int e = 0; e < 4; ++e) {
                    if (j + e < N) {
                        int c = labels[j + e];
                        atomicMax(&accr[c], enc(values[rowoff + j + e]));
                    }
                }
            }
        }
    }

    __syncthreads();

    // Flush per-block partials into global encoded output.
    for (int i = tid; i < rmax * C; i += TPB) {
        int r = i / C, c = i - r * C;
        atomicMax(&out_enc[(size_t)(row0 + r) * C + c], acc[r * CPAD + c]);
    }
}

__global__ __launch_bounds__(TPB) void strat_decode(unsigned* __restrict__ buf, int n) {
    int i = blockIdx.x * TPB + threadIdx.x;
    if (i < n) {
        float f = dec(buf[i]);
        ((float*)buf)[i] = f;
    }
}

extern "C" void kernel_launch(void* const* d_in, const int* in_sizes, int n_in,
                              void* d_out, int out_size, void* d_ws, size_t ws_size,
                              hipStream_t stream) {
    const float* values = (const float*)d_in[0];
    const int*   labels = (const int*)d_in[1];
    // d_in[2] = num_classes scalar; C is also derivable host-side:
    const int N = in_sizes[1];
    const int B = in_sizes[0] / N;
    const int C = out_size / B;

    unsigned* out_enc = (unsigned*)d_out;

    int init_blocks = (out_size + TPB - 1) / TPB;
    strat_init<<<init_blocks, TPB, 0, stream>>>(out_enc, out_size);

    dim3 grid((N + CHUNK - 1) / CHUNK, (B + ROWS - 1) / ROWS);
    strat_main<<<grid, TPB, 0, stream>>>(values, labels, out_enc, B, N, C);

    strat_decode<<<init_blocks, TPB, 0, stream>>>(out_enc, out_size);
}